// Round 6
// baseline (675.456 us; speedup 1.0000x reference)
//
#include <hip/hip_runtime.h>
#include <hip/hip_bf16.h>
#include <stdint.h>

typedef unsigned short u16;
typedef unsigned int u32;
typedef __attribute__((ext_vector_type(8))) __bf16 bf16x8;
typedef __attribute__((ext_vector_type(8))) unsigned short us8;
typedef __attribute__((ext_vector_type(4))) unsigned short us4;
typedef __attribute__((ext_vector_type(4))) float f32x4;
typedef __attribute__((ext_vector_type(16))) float f32x16;
typedef __attribute__((ext_vector_type(4))) unsigned int u32x4;
typedef __attribute__((ext_vector_type(2))) unsigned int u32x2;

#define KSCALE_Q 0.18033688011112042f  /* (1/8) * log2(e) */

__device__ inline u16 f2bf(float f) {
  union { __bf16 b; u16 s; } x; x.b = (__bf16)f; return x.s;
}
__device__ inline u32 packbf(float a, float b) {
  return (u32)f2bf(a) | ((u32)f2bf(b) << 16);
}
__device__ inline f32x16 zero16() {
  f32x16 z; for (int i = 0; i < 16; ++i) z[i] = 0.f; return z;
}
__device__ __forceinline__ void gl_lds16(const u16* g, u16* l) {
  __builtin_amdgcn_global_load_lds(
      (const __attribute__((address_space(1))) void*)g,
      (__attribute__((address_space(3))) void*)l, 16, 0, 0);
}
// Exchange: new a = [a.lo32 | b.lo32], new b = [a.hi32 | b.hi32]
__device__ __forceinline__ void pl32swap(u32& a, u32& b) {
#if __has_builtin(__builtin_amdgcn_permlane32_swap)
  u32x2 r = __builtin_amdgcn_permlane32_swap(a, b, false, false);
  a = r[0]; b = r[1];
#else
  u32 ta = (u32)__shfl_xor((int)a, 32);
  u32 tb = (u32)__shfl_xor((int)b, 32);
  int hi = (threadIdx.x & 63) >> 5;
  u32 na = hi ? tb : a;
  u32 nb = hi ? b : ta;
  a = na; b = nb;
#endif
}

// ---------------------------------------------------------------- prep (fused)
__global__ __launch_bounds__(256) void prep(
    const float* __restrict__ x, const float* __restrict__ Wc,
    const float* __restrict__ Wo, const int* __restrict__ mask,
    u16* __restrict__ xbf, u16* __restrict__ wct, u16* __restrict__ wot,
    int* __restrict__ idx, int* __restrict__ nbv) {
  int r = blockIdx.x, tid = threadIdx.x;
  if (r < 4096) {
    int i = r * 256 + tid;
    float4 v = ((const float4*)x)[i];
    us4 o;
    o[0] = f2bf(v.x); o[1] = f2bf(v.y); o[2] = f2bf(v.z); o[3] = f2bf(v.w);
    ((us4*)xbf)[i] = o;
    return;
  }
  __shared__ float tile[32][33];
  __shared__ int ps[256];
  if (r < 5120) {
    const float* in; u16* outT; int R, C, bi;
    if (r < 4864) { in = Wc; outT = wct; R = 512; C = 1536; bi = r - 4096; }
    else          { in = Wo; outT = wot; R = 512; C = 512;  bi = r - 4864; }
    int nbx = C >> 5;
    int bx = bi % nbx, by = bi / nbx;
    int xq = tid & 31, yq = tid >> 5;
    int c0 = bx * 32, r0 = by * 32;
    for (int j = 0; j < 32; j += 8)
      tile[yq + j][xq] = in[(size_t)(r0 + yq + j) * C + c0 + xq];
    __syncthreads();
    for (int j = 0; j < 32; j += 8)
      outT[(size_t)(c0 + yq + j) * R + r0 + xq] = f2bf(tile[xq][yq + j]);
    return;
  }
  int b = r - 5120;
  const int* mrow = mask + b * 2048;
  int4 a = ((const int4*)mrow)[tid * 2];
  int4 c = ((const int4*)mrow)[tid * 2 + 1];
  int v[8] = {a.x, a.y, a.z, a.w, c.x, c.y, c.z, c.w};
  int cnt = 0;
  for (int i = 0; i < 8; ++i) cnt += (v[i] > 0);
  ps[tid] = cnt;
  __syncthreads();
  for (int off = 1; off < 256; off <<= 1) {
    int xv = ps[tid];
    int yv = (tid >= off) ? ps[tid - off] : 0;
    __syncthreads();
    ps[tid] = xv + yv;
    __syncthreads();
  }
  int total = ps[255];
  int pos = ps[tid] - cnt;
  int* ip = idx + b * 2048;
  for (int i = 0; i < 8; ++i)
    if (v[i] > 0) ip[pos++] = tid * 8 + i;
  for (int i = 0; i < 8; ++i) {
    int j = tid * 8 + i;
    if (j >= total) ip[j] = 0;
  }
  if (tid == 0) nbv[b] = total;
}

// ---------------------------------------------------------------- QKV GEMM
// One launch: blocks [0,512) = Q projection (M=8192, cols 0..511 of Wc^T,
// output Qc scaled by log2e/8); blocks [512,1536) = KV projection over
// gathered compact keys (cols 512..1535), K -> Kc, V -> VTc transposed.
__global__ __launch_bounds__(256) void gemm_qkv(
    const u16* __restrict__ A, const u16* __restrict__ Bt,
    const float* __restrict__ bias, u16* __restrict__ Qc,
    u16* __restrict__ Kc, u16* __restrict__ VTc,
    const int* __restrict__ idx, const int* __restrict__ nbv) {
  const int K = 512;
  int bid = blockIdx.x;
  bool isQ = bid < 512;
  int b = 0, m0, n0;
  if (isQ) {
    n0 = (bid & 7) * 64;
    m0 = (bid >> 3) * 128;
  } else {
    int t = bid - 512;
    b = t >> 8;
    int rr_ = t & 255;
    m0 = (rr_ & 15) * 128;
    n0 = ((rr_ >> 4) * 64) + 512;
    int npad = (nbv[b] + 127) & ~127;
    if (m0 >= npad) return;
  }
  __shared__ __align__(16) u16 As[128 * 64];
  __shared__ __align__(16) u16 Bs[64 * 64];
  int tid = threadIdx.x, wave = tid >> 6, lane = tid & 63;
  int quad = lane >> 4, l16 = lane & 15;
  int wm = (wave >> 1) * 64, wn = (wave & 1) * 32;

  int r8 = lane >> 3;
  int cb = (lane & 7) ^ r8;
  const u16* agp[4];
  for (int i = 0; i < 4; ++i) {
    int row = m0 + wave * 32 + i * 8 + r8;
    int grow = isQ ? row : (b * 2048 + idx[b * 2048 + row]);
    agp[i] = A + (size_t)grow * K + cb * 8;
  }
  const u16* bg = Bt + (size_t)(n0 + wave * 16 + r8) * K + cb * 8;
  u16* al = As + (wave * 32) * 64 + lane * 8;
  u16* bl = Bs + (wave * 16) * 64 + lane * 8;

  f32x4 acc[4][2];
  for (int i = 0; i < 4; ++i)
    for (int j = 0; j < 2; ++j) acc[i][j] = (f32x4){0.f, 0.f, 0.f, 0.f};

  int rx = l16 & 7;
  for (int kk = 0; kk < K; kk += 64) {
    __syncthreads();
    for (int i = 0; i < 4; ++i)
      gl_lds16(agp[i] + kk, al + i * 8 * 64);
    for (int i = 0; i < 2; ++i)
      gl_lds16(bg + kk + (size_t)(i * 8) * K, bl + i * 8 * 64);
    __syncthreads();
    for (int ks = 0; ks < 2; ++ks) {
      int pos = ((ks * 4 + quad) ^ rx) * 8;
      bf16x8 af[4], bfr[2];
      for (int i = 0; i < 4; ++i)
        af[i] = *(const bf16x8*)(As + (wm + i * 16 + l16) * 64 + pos);
      for (int j = 0; j < 2; ++j)
        bfr[j] = *(const bf16x8*)(Bs + (wn + j * 16 + l16) * 64 + pos);
      for (int i = 0; i < 4; ++i)
        for (int j = 0; j < 2; ++j)
          acc[i][j] = __builtin_amdgcn_mfma_f32_16x16x32_bf16(
              af[i], bfr[j], acc[i][j], 0, 0, 0);
    }
  }
  for (int j = 0; j < 2; ++j) {
    int col = n0 + wn + j * 16 + l16;
    float bv = bias[col];
    if (isQ) {
      for (int i = 0; i < 4; ++i) {
        int rowb = m0 + wm + i * 16 + quad * 4;
        for (int rr = 0; rr < 4; ++rr)
          Qc[(size_t)(rowb + rr) * 512 + col] =
              f2bf((acc[i][j][rr] + bv) * KSCALE_Q);
      }
    } else if (col < 1024) {  // K half
      int ck = col - 512;
      for (int i = 0; i < 4; ++i) {
        int key0 = m0 + wm + i * 16 + quad * 4;
        for (int rr = 0; rr < 4; ++rr)
          Kc[((size_t)b * 2048 + key0 + rr) * 512 + ck] =
              f2bf(acc[i][j][rr] + bv);
      }
    } else {  // V half -> transposed
      int hd = col - 1024;
      int h = hd >> 6, d = hd & 63;
      u16* vrow = VTc + ((size_t)(b * 8 + h) * 64 + d) * 2048;
      for (int i = 0; i < 4; ++i) {
        int key0 = m0 + wm + i * 16 + quad * 4;
        us4 pk;
        for (int rr = 0; rr < 4; ++rr) pk[rr] = f2bf(acc[i][j][rr] + bv);
        *(us4*)(vrow + key0) = pk;
      }
    }
  }
}

// ---------------------------------------------------------------- out GEMM
__global__ __launch_bounds__(256) void gemm_out(
    const u16* __restrict__ A, const u16* __restrict__ Bt,
    const float* __restrict__ bias, float* __restrict__ Cout) {
  const int K = 512, N = 512;
  int m0 = blockIdx.y * 128, n0 = blockIdx.x * 64;
  __shared__ __align__(16) u16 As[128 * 64];
  __shared__ __align__(16) u16 Bs[64 * 64];
  int tid = threadIdx.x, wave = tid >> 6, lane = tid & 63;
  int quad = lane >> 4, l16 = lane & 15;
  int wm = (wave >> 1) * 64, wn = (wave & 1) * 32;

  int r8 = lane >> 3;
  int cb = (lane & 7) ^ r8;
  const u16* ag = A + (size_t)(m0 + wave * 32 + r8) * K + cb * 8;
  const u16* bg = Bt + (size_t)(n0 + wave * 16 + r8) * K + cb * 8;
  u16* al = As + (wave * 32) * 64 + lane * 8;
  u16* bl = Bs + (wave * 16) * 64 + lane * 8;

  f32x4 acc[4][2];
  for (int i = 0; i < 4; ++i)
    for (int j = 0; j < 2; ++j) acc[i][j] = (f32x4){0.f, 0.f, 0.f, 0.f};

  int rx = l16 & 7;
  for (int kk = 0; kk < K; kk += 64) {
    __syncthreads();
    for (int i = 0; i < 4; ++i)
      gl_lds16(ag + kk + (size_t)(i * 8) * K, al + i * 8 * 64);
    for (int i = 0; i < 2; ++i)
      gl_lds16(bg + kk + (size_t)(i * 8) * K, bl + i * 8 * 64);
    __syncthreads();
    for (int ks = 0; ks < 2; ++ks) {
      int pos = ((ks * 4 + quad) ^ rx) * 8;
      bf16x8 af[4], bfr[2];
      for (int i = 0; i < 4; ++i)
        af[i] = *(const bf16x8*)(As + (wm + i * 16 + l16) * 64 + pos);
      for (int j = 0; j < 2; ++j)
        bfr[j] = *(const bf16x8*)(Bs + (wn + j * 16 + l16) * 64 + pos);
      for (int i = 0; i < 4; ++i)
        for (int j = 0; j < 2; ++j)
          acc[i][j] = __builtin_amdgcn_mfma_f32_16x16x32_bf16(
              af[i], bfr[j], acc[i][j], 0, 0, 0);
    }
  }
  for (int j = 0; j < 2; ++j) {
    int col = n0 + wn + j * 16 + l16;
    float bv = bias[col];
    for (int i = 0; i < 4; ++i) {
      int rowb = m0 + wm + i * 16 + quad * 4;
      for (int rr = 0; rr < 4; ++rr)
        Cout[(size_t)(rowb + rr) * N + col] = acc[i][j][rr] + bv;
    }
  }
}

// ---------------------------------------------------------------- attention
// LDS-free flash: K/V fragments loaded directly global(L2)->VGPR (contiguous
// 16B runs by construction). No barriers. 32x32x16 MFMA, wave = 32 q,
// 128-key tiles, no-max exp2 softmax, P via permlane32_swap.
__global__ __launch_bounds__(256) void attn_kernel(
    const u16* __restrict__ Qc, const u16* __restrict__ Kc,
    const u16* __restrict__ VTc, const int* __restrict__ nbv,
    u16* __restrict__ aout) {
  int b = blockIdx.z, h = blockIdx.y, q0 = blockIdx.x * 128;
  int bh = b * 8 + h;
  int tid = threadIdx.x, wave = tid >> 6, lane = tid & 63;
  int l5 = lane & 31, hi = lane >> 5;
  int nb = nbv[b];
  int npad = (nb + 127) & ~127;

  int qrow = b * 2048 + q0 + wave * 32 + l5;
  bf16x8 qf[4];  // B-op: k = s*16 + hi*8 + j, n = q = l5
  for (int s = 0; s < 4; ++s)
    qf[s] = *(const bf16x8*)(Qc + (size_t)qrow * 512 + h * 64 + s * 16 + hi * 8);

  f32x16 o0 = zero16(), o1 = zero16();
  float lsum = 0.f;

  // lane-resident base pointers; every fragment is 16B contiguous in global.
  const u16* kb = Kc + ((size_t)b * 2048 + l5) * 512 + h * 64 + hi * 8;
  const u16* vb0 = VTc + ((size_t)bh * 64 + l5) * 2048 + hi * 8;
  const u16* vb1 = vb0 + (size_t)32 * 2048;

  for (int kt0 = 0; kt0 < npad; kt0 += 128) {
    bf16x8 pb[8];
    for (int kg4 = 0; kg4 < 4; ++kg4) {
      const u16* kr = kb + (size_t)(kt0 + kg4 * 32) * 512;
      bf16x8 ka0 = *(const bf16x8*)(kr);
      bf16x8 ka1 = *(const bf16x8*)(kr + 16);
      bf16x8 ka2 = *(const bf16x8*)(kr + 32);
      bf16x8 ka3 = *(const bf16x8*)(kr + 48);
      f32x16 sa = zero16();
      sa = __builtin_amdgcn_mfma_f32_32x32x16_bf16(ka0, qf[0], sa, 0, 0, 0);
      sa = __builtin_amdgcn_mfma_f32_32x32x16_bf16(ka1, qf[1], sa, 0, 0, 0);
      sa = __builtin_amdgcn_mfma_f32_32x32x16_bf16(ka2, qf[2], sa, 0, 0, 0);
      sa = __builtin_amdgcn_mfma_f32_32x32x16_bf16(ka3, qf[3], sa, 0, 0, 0);
      if (kt0 + 128 > nb) {  // uniform: only final tile masks
        for (int r = 0; r < 16; ++r) {
          int jg = kt0 + kg4 * 32 + (r & 3) + 8 * (r >> 2) + 4 * hi;
          if (jg >= nb) sa[r] = -1e30f;
        }
      }
      u32 pk[8];
      for (int j = 0; j < 8; ++j) {
        float e0 = __builtin_amdgcn_exp2f(sa[2 * j]);
        float e1 = __builtin_amdgcn_exp2f(sa[2 * j + 1]);
        lsum += e0 + e1;
        pk[j] = packbf(e0, e1);
      }
      for (int t = 0; t < 2; ++t) {
        u32 a0 = pk[t * 4 + 0], a2 = pk[t * 4 + 2];
        u32 a1 = pk[t * 4 + 1], a3 = pk[t * 4 + 3];
        pl32swap(a0, a2);
        pl32swap(a1, a3);
        u32x4 qv; qv[0] = a0; qv[1] = a1; qv[2] = a2; qv[3] = a3;
        pb[kg4 * 2 + t] = __builtin_bit_cast(bf16x8, qv);
      }
    }
    for (int kg4 = 0; kg4 < 4; ++kg4)
      for (int t = 0; t < 2; ++t) {
        int koff = kt0 + (kg4 * 4 + t * 2) * 8;
        bf16x8 va0 = *(const bf16x8*)(vb0 + koff);
        bf16x8 va1 = *(const bf16x8*)(vb1 + koff);
        o0 = __builtin_amdgcn_mfma_f32_32x32x16_bf16(va0, pb[kg4 * 2 + t], o0,
                                                     0, 0, 0);
        o1 = __builtin_amdgcn_mfma_f32_32x32x16_bf16(va1, pb[kg4 * 2 + t], o1,
                                                     0, 0, 0);
      }
  }

  lsum += __shfl_xor(lsum, 32);
  float inv = 1.f / lsum;
  f32x16 oo[2]; oo[0] = o0; oo[1] = o1;
  for (int dc = 0; dc < 2; ++dc)
    for (int mI = 0; mI < 4; ++mI) {
      us4 pk;
      for (int r = 0; r < 4; ++r) pk[r] = f2bf(oo[dc][mI * 4 + r] * inv);
      *(us4*)(aout + (size_t)qrow * 512 + h * 64 + dc * 32 + mI * 8 + hi * 4) =
          pk;
    }
}

// ---------------------------------------------------------------- launch
extern "C" void kernel_launch(void* const* d_in, const int* in_sizes, int n_in,
                              void* d_out, int out_size, void* d_ws,
                              size_t ws_size, hipStream_t stream) {
  const float* x = (const float*)d_in[0];     // [4,2048,512]
  const int* mask = (const int*)d_in[1];      // [4,2048]
  const float* Wc = (const float*)d_in[2];    // [512,1536]
  const float* bc = (const float*)d_in[3];    // [1536]
  const float* Wo = (const float*)d_in[4];    // [512,512]
  const float* bo = (const float*)d_in[5];    // [512]
  float* out = (float*)d_out;                 // [4,2048,512] fp32

  char* ws = (char*)d_ws;
  u16* xbf = (u16*)(ws);                      //  8 MB [8192][512]
  u16* wct = (u16*)(ws + 8388608);            //  1.5 MB [1536][512]
  u16* wot = (u16*)(ws + 9961472);            //  0.5 MB [512][512]
  u16* Qc  = (u16*)(ws + 10485760);           //  8 MB (pre-scaled by log2e/8)
  u16* Kc  = (u16*)(ws + 18874368);           //  8 MB compact K
  u16* vtc = (u16*)(ws + 27262976);           //  8 MB compact V^T
  int* idx = (int*)(ws + 35651584);           // 32 KB
  int* nbv = (int*)(ws + 35684352);           // 16 B
  u16* aout = xbf;                            // reuse (xbf dead after gemms)

  prep<<<5124, 256, 0, stream>>>(x, Wc, Wo, mask, xbf, wct, wot, idx, nbv);
  gemm_qkv<<<1536, 256, 0, stream>>>(xbf, wct, bc, Qc, Kc, vtc, idx, nbv);
  attn_kernel<<<dim3(16, 8, 4), 256, 0, stream>>>(Qc, Kc, vtc, nbv, aout);
  gemm_out<<<dim3(8, 64), 256, 0, stream>>>(aout, wot, bo, out);
}

// Round 7
// 156.396 us; speedup vs baseline: 4.3189x; 4.3189x over previous
//
#include <hip/hip_runtime.h>
#include <hip/hip_bf16.h>
#include <stdint.h>

typedef unsigned short u16;
typedef unsigned int u32;
typedef __attribute__((ext_vector_type(8))) __bf16 bf16x8;
typedef __attribute__((ext_vector_type(8))) unsigned short us8;
typedef __attribute__((ext_vector_type(4))) unsigned short us4;
typedef __attribute__((ext_vector_type(4))) float f32x4;
typedef __attribute__((ext_vector_type(16))) float f32x16;
typedef __attribute__((ext_vector_type(4))) unsigned int u32x4;
typedef __attribute__((ext_vector_type(2))) unsigned int u32x2;

#define KSCALE_Q 0.18033688011112042f  /* (1/8) * log2(e) */

__device__ inline u16 f2bf(float f) {
  union { __bf16 b; u16 s; } x; x.b = (__bf16)f; return x.s;
}
__device__ inline u32 packbf(float a, float b) {
  return (u32)f2bf(a) | ((u32)f2bf(b) << 16);
}
__device__ inline f32x16 zero16() {
  f32x16 z; for (int i = 0; i < 16; ++i) z[i] = 0.f; return z;
}
__device__ __forceinline__ void gl_lds16(const u16* g, u16* l) {
  __builtin_amdgcn_global_load_lds(
      (const __attribute__((address_space(1))) void*)g,
      (__attribute__((address_space(3))) void*)l, 16, 0, 0);
}
// Exchange: new a = [a.lo32 | b.lo32], new b = [a.hi32 | b.hi32]
__device__ __forceinline__ void pl32swap(u32& a, u32& b) {
#if __has_builtin(__builtin_amdgcn_permlane32_swap)
  u32x2 r = __builtin_amdgcn_permlane32_swap(a, b, false, false);
  a = r[0]; b = r[1];
#else
  u32 ta = (u32)__shfl_xor((int)a, 32);
  u32 tb = (u32)__shfl_xor((int)b, 32);
  int hi = (threadIdx.x & 63) >> 5;
  u32 na = hi ? tb : a;
  u32 nb = hi ? b : ta;
  a = na; b = nb;
#endif
}

// ---------------------------------------------------------------- prep (fused)
__global__ __launch_bounds__(256) void prep(
    const float* __restrict__ x, const float* __restrict__ Wc,
    const float* __restrict__ Wo, const int* __restrict__ mask,
    u16* __restrict__ xbf, u16* __restrict__ wct, u16* __restrict__ wot,
    int* __restrict__ idx, int* __restrict__ nbv) {
  int r = blockIdx.x, tid = threadIdx.x;
  if (r < 4096) {
    int i = r * 256 + tid;
    float4 v = ((const float4*)x)[i];
    us4 o;
    o[0] = f2bf(v.x); o[1] = f2bf(v.y); o[2] = f2bf(v.z); o[3] = f2bf(v.w);
    ((us4*)xbf)[i] = o;
    return;
  }
  __shared__ float tile[32][33];
  __shared__ int ps[256];
  if (r < 5120) {
    const float* in; u16* outT; int R, C, bi;
    if (r < 4864) { in = Wc; outT = wct; R = 512; C = 1536; bi = r - 4096; }
    else          { in = Wo; outT = wot; R = 512; C = 512;  bi = r - 4864; }
    int nbx = C >> 5;
    int bx = bi % nbx, by = bi / nbx;
    int xq = tid & 31, yq = tid >> 5;
    int c0 = bx * 32, r0 = by * 32;
    for (int j = 0; j < 32; j += 8)
      tile[yq + j][xq] = in[(size_t)(r0 + yq + j) * C + c0 + xq];
    __syncthreads();
    for (int j = 0; j < 32; j += 8)
      outT[(size_t)(c0 + yq + j) * R + r0 + xq] = f2bf(tile[xq][yq + j]);
    return;
  }
  int b = r - 5120;
  const int* mrow = mask + b * 2048;
  int4 a = ((const int4*)mrow)[tid * 2];
  int4 c = ((const int4*)mrow)[tid * 2 + 1];
  int v[8] = {a.x, a.y, a.z, a.w, c.x, c.y, c.z, c.w};
  int cnt = 0;
  for (int i = 0; i < 8; ++i) cnt += (v[i] > 0);
  ps[tid] = cnt;
  __syncthreads();
  for (int off = 1; off < 256; off <<= 1) {
    int xv = ps[tid];
    int yv = (tid >= off) ? ps[tid - off] : 0;
    __syncthreads();
    ps[tid] = xv + yv;
    __syncthreads();
  }
  int total = ps[255];
  int pos = ps[tid] - cnt;
  int* ip = idx + b * 2048;
  for (int i = 0; i < 8; ++i)
    if (v[i] > 0) ip[pos++] = tid * 8 + i;
  for (int i = 0; i < 8; ++i) {
    int j = tid * 8 + i;
    if (j >= total) ip[j] = 0;
  }
  if (tid == 0) nbv[b] = total;
}

// ---------------------------------------------------------------- QKV GEMM
// 128x128 tiles, BK=64 (m97 shape). blocks [0,256) = Q projection;
// [256,768) = KV over gathered compact keys (K -> Kc, V -> VTc transposed).
__global__ __launch_bounds__(256) void gemm_qkv(
    const u16* __restrict__ A, const u16* __restrict__ Bt,
    const float* __restrict__ bias, u16* __restrict__ Qc,
    u16* __restrict__ Kc, u16* __restrict__ VTc,
    const int* __restrict__ idx, const int* __restrict__ nbv) {
  const int K = 512;
  int bid = blockIdx.x;
  bool isQ = bid < 256;
  int b = 0, m0, n0;
  if (isQ) {
    m0 = (bid >> 2) * 128;
    n0 = (bid & 3) * 128;
  } else {
    int t = bid - 256;
    b = t >> 7;
    int rr_ = t & 127;
    m0 = (rr_ & 15) * 128;
    n0 = (rr_ >> 4) * 128 + 512;
    int npad = (nbv[b] + 127) & ~127;
    if (m0 >= npad) return;
  }
  __shared__ __align__(16) u16 As[128 * 64];  // 16 KB
  __shared__ __align__(16) u16 Bs[128 * 64];  // 16 KB
  int tid = threadIdx.x, wave = tid >> 6, lane = tid & 63;
  int quad = lane >> 4, l16 = lane & 15;
  int wm = (wave >> 1) * 64, wn = (wave & 1) * 64;

  int r8 = lane >> 3;
  int cb = (lane & 7) ^ r8;
  const u16* agp[4];
  for (int i = 0; i < 4; ++i) {
    int row = m0 + wave * 32 + i * 8 + r8;
    int grow = isQ ? row : (b * 2048 + idx[b * 2048 + row]);
    agp[i] = A + (size_t)grow * K + cb * 8;
  }
  const u16* bg = Bt + (size_t)(n0 + wave * 32 + r8) * K + cb * 8;
  u16* al = As + (wave * 32) * 64 + lane * 8;
  u16* bl = Bs + (wave * 32) * 64 + lane * 8;

  f32x4 acc[4][4];
  for (int i = 0; i < 4; ++i)
    for (int j = 0; j < 4; ++j) acc[i][j] = (f32x4){0.f, 0.f, 0.f, 0.f};

  int rx = l16 & 7;
  for (int kk = 0; kk < K; kk += 64) {
    __syncthreads();
    for (int i = 0; i < 4; ++i)
      gl_lds16(agp[i] + kk, al + i * 8 * 64);
    for (int i = 0; i < 4; ++i)
      gl_lds16(bg + kk + (size_t)(i * 8) * K, bl + i * 8 * 64);
    __syncthreads();
    for (int ks = 0; ks < 2; ++ks) {
      int pos = ((ks * 4 + quad) ^ rx) * 8;
      bf16x8 af[4], bfr[4];
      for (int i = 0; i < 4; ++i)
        af[i] = *(const bf16x8*)(As + (wm + i * 16 + l16) * 64 + pos);
      for (int j = 0; j < 4; ++j)
        bfr[j] = *(const bf16x8*)(Bs + (wn + j * 16 + l16) * 64 + pos);
      for (int i = 0; i < 4; ++i)
        for (int j = 0; j < 4; ++j)
          acc[i][j] = __builtin_amdgcn_mfma_f32_16x16x32_bf16(
              af[i], bfr[j], acc[i][j], 0, 0, 0);
    }
  }
  for (int j = 0; j < 4; ++j) {
    int col = n0 + wn + j * 16 + l16;
    float bv = bias[col];
    if (isQ) {
      for (int i = 0; i < 4; ++i) {
        int rowb = m0 + wm + i * 16 + quad * 4;
        for (int rr = 0; rr < 4; ++rr)
          Qc[(size_t)(rowb + rr) * 512 + col] =
              f2bf((acc[i][j][rr] + bv) * KSCALE_Q);
      }
    } else if (col < 1024) {  // K half
      int ck = col - 512;
      for (int i = 0; i < 4; ++i) {
        int key0 = m0 + wm + i * 16 + quad * 4;
        for (int rr = 0; rr < 4; ++rr)
          Kc[((size_t)b * 2048 + key0 + rr) * 512 + ck] =
              f2bf(acc[i][j][rr] + bv);
      }
    } else {  // V half -> transposed
      int hd = col - 1024;
      int h = hd >> 6, d = hd & 63;
      u16* vrow = VTc + ((size_t)(b * 8 + h) * 64 + d) * 2048;
      for (int i = 0; i < 4; ++i) {
        int key0 = m0 + wm + i * 16 + quad * 4;
        us4 pk;
        for (int rr = 0; rr < 4; ++rr) pk[rr] = f2bf(acc[i][j][rr] + bv);
        *(us4*)(vrow + key0) = pk;
      }
    }
  }
}

// ---------------------------------------------------------------- out GEMM
// 128x128 tiles, BK=64.
__global__ __launch_bounds__(256) void gemm_out(
    const u16* __restrict__ A, const u16* __restrict__ Bt,
    const float* __restrict__ bias, float* __restrict__ Cout) {
  const int K = 512, N = 512;
  int m0 = blockIdx.y * 128, n0 = blockIdx.x * 128;
  __shared__ __align__(16) u16 As[128 * 64];
  __shared__ __align__(16) u16 Bs[128 * 64];
  int tid = threadIdx.x, wave = tid >> 6, lane = tid & 63;
  int quad = lane >> 4, l16 = lane & 15;
  int wm = (wave >> 1) * 64, wn = (wave & 1) * 64;

  int r8 = lane >> 3;
  int cb = (lane & 7) ^ r8;
  const u16* ag = A + (size_t)(m0 + wave * 32 + r8) * K + cb * 8;
  const u16* bg = Bt + (size_t)(n0 + wave * 32 + r8) * K + cb * 8;
  u16* al = As + (wave * 32) * 64 + lane * 8;
  u16* bl = Bs + (wave * 32) * 64 + lane * 8;

  f32x4 acc[4][4];
  for (int i = 0; i < 4; ++i)
    for (int j = 0; j < 4; ++j) acc[i][j] = (f32x4){0.f, 0.f, 0.f, 0.f};

  int rx = l16 & 7;
  for (int kk = 0; kk < K; kk += 64) {
    __syncthreads();
    for (int i = 0; i < 4; ++i)
      gl_lds16(ag + kk + (size_t)(i * 8) * K, al + i * 8 * 64);
    for (int i = 0; i < 4; ++i)
      gl_lds16(bg + kk + (size_t)(i * 8) * K, bl + i * 8 * 64);
    __syncthreads();
    for (int ks = 0; ks < 2; ++ks) {
      int pos = ((ks * 4 + quad) ^ rx) * 8;
      bf16x8 af[4], bfr[4];
      for (int i = 0; i < 4; ++i)
        af[i] = *(const bf16x8*)(As + (wm + i * 16 + l16) * 64 + pos);
      for (int j = 0; j < 4; ++j)
        bfr[j] = *(const bf16x8*)(Bs + (wn + j * 16 + l16) * 64 + pos);
      for (int i = 0; i < 4; ++i)
        for (int j = 0; j < 4; ++j)
          acc[i][j] = __builtin_amdgcn_mfma_f32_16x16x32_bf16(
              af[i], bfr[j], acc[i][j], 0, 0, 0);
    }
  }
  for (int j = 0; j < 4; ++j) {
    int col = n0 + wn + j * 16 + l16;
    float bv = bias[col];
    for (int i = 0; i < 4; ++i) {
      int rowb = m0 + wm + i * 16 + quad * 4;
      for (int rr = 0; rr < 4; ++rr)
        Cout[(size_t)(rowb + rr) * N + col] = acc[i][j][rr] + bv;
    }
  }
}

// ---------------------------------------------------------------- attention
// LDS-staged flash (r5 structure), 64 q per wave (2 q-groups sharing all
// K/V fragment reads). 128-key tiles, 32x32x16 MFMA, no-max exp2 softmax,
// P C->B operand via permlane32_swap. Block = 4 waves = 256 q.
__global__ __launch_bounds__(256) void attn_kernel(
    const u16* __restrict__ Qc, const u16* __restrict__ Kc,
    const u16* __restrict__ VTc, const int* __restrict__ nbv,
    u16* __restrict__ aout) {
  int b = blockIdx.z, h = blockIdx.y, q0 = blockIdx.x * 256;
  int bh = b * 8 + h;
  int tid = threadIdx.x, wave = tid >> 6, lane = tid & 63;
  int l5 = lane & 31, hi = lane >> 5;
  int nb = nbv[b];
  int npad = (nb + 127) & ~127;

  __shared__ __align__(16) u16 Kt[128 * 64];  // [key][d], XOR8 16B blocks
  __shared__ __align__(16) u16 Vt[64 * 128];  // [d][key], XOR16 16B blocks

  bf16x8 qf[2][4];  // B-op: k = s*16 + hi*8 + j, n = q = l5
  for (int qg = 0; qg < 2; ++qg) {
    int qrow = b * 2048 + q0 + wave * 64 + qg * 32 + l5;
    for (int s = 0; s < 4; ++s)
      qf[qg][s] = *(const bf16x8*)(Qc + (size_t)qrow * 512 + h * 64 + s * 16 +
                                   hi * 8);
  }

  f32x16 o[2][2];
  for (int qg = 0; qg < 2; ++qg)
    for (int dc = 0; dc < 2; ++dc) o[qg][dc] = zero16();
  float lsum[2] = {0.f, 0.f};

  // K staging: 8 rows/instr (128B rows); V: 4 rows/instr (256B rows)
  int krr = lane >> 3;
  int kcb = (lane & 7) ^ krr;
  const u16* kg = Kc + ((size_t)(b * 2048) + wave * 32 + krr) * 512 + h * 64 +
                  kcb * 8;
  u16* kl = Kt + (wave * 32) * 64 + lane * 8;
  int vrr = lane >> 4;
  u16* vl = Vt + (wave * 16) * 128 + lane * 8;

  for (int kt0 = 0; kt0 < npad; kt0 += 128) {
    __syncthreads();
    for (int i = 0; i < 4; ++i)
      gl_lds16(kg + (size_t)(kt0 + i * 8) * 512, kl + i * 8 * 64);
    for (int i = 0; i < 4; ++i) {
      int vr = wave * 16 + i * 4 + vrr;
      int vcb = (lane & 15) ^ (vr & 15);
      gl_lds16(VTc + ((size_t)(bh * 64) + vr) * 2048 + kt0 + vcb * 8,
               vl + i * 4 * 128);
    }
    __syncthreads();

    for (int kg4 = 0; kg4 < 4; ++kg4) {
      int krow = kg4 * 32 + l5;
      const u16* kro = Kt + krow * 64;
      int rx = krow & 7;
      bf16x8 ka[4];
      for (int s = 0; s < 4; ++s)
        ka[s] = *(const bf16x8*)(kro + ((s * 2 + hi) ^ rx) * 8);
      bf16x8 pb[2][2];
      for (int qg = 0; qg < 2; ++qg) {
        f32x16 sa = zero16();
        for (int s = 0; s < 4; ++s)
          sa = __builtin_amdgcn_mfma_f32_32x32x16_bf16(ka[s], qf[qg][s], sa,
                                                       0, 0, 0);
        if (kt0 + 128 > nb) {  // uniform: only final tile masks
          for (int r = 0; r < 16; ++r) {
            int jg = kt0 + kg4 * 32 + (r & 3) + 8 * (r >> 2) + 4 * hi;
            if (jg >= nb) sa[r] = -1e30f;
          }
        }
        u32 pk[8];
        float ls = 0.f;
        for (int j = 0; j < 8; ++j) {
          float e0 = __builtin_amdgcn_exp2f(sa[2 * j]);
          float e1 = __builtin_amdgcn_exp2f(sa[2 * j + 1]);
          ls += e0 + e1;
          pk[j] = packbf(e0, e1);
        }
        lsum[qg] += ls;
        for (int t = 0; t < 2; ++t) {
          u32 a0 = pk[t * 4 + 0], a2 = pk[t * 4 + 2];
          u32 a1 = pk[t * 4 + 1], a3 = pk[t * 4 + 3];
          pl32swap(a0, a2);
          pl32swap(a1, a3);
          u32x4 qv; qv[0] = a0; qv[1] = a1; qv[2] = a2; qv[3] = a3;
          pb[qg][t] = __builtin_bit_cast(bf16x8, qv);
        }
      }
      for (int t = 0; t < 2; ++t) {
        int cblk = kg4 * 4 + t * 2 + hi;
        for (int dc = 0; dc < 2; ++dc) {
          int vrow = dc * 32 + l5;
          bf16x8 va = *(const bf16x8*)(Vt + vrow * 128 +
                                       ((cblk ^ (vrow & 15)) * 8));
          for (int qg = 0; qg < 2; ++qg)
            o[qg][dc] = __builtin_amdgcn_mfma_f32_32x32x16_bf16(
                va, pb[qg][t], o[qg][dc], 0, 0, 0);
        }
      }
    }
  }

  for (int qg = 0; qg < 2; ++qg) {
    float lt = lsum[qg];
    lt += __shfl_xor(lt, 32);
    float inv = 1.f / lt;
    int qrow = b * 2048 + q0 + wave * 64 + qg * 32 + l5;
    for (int dc = 0; dc < 2; ++dc)
      for (int mI = 0; mI < 4; ++mI) {
        us4 pk;
        for (int r = 0; r < 4; ++r) pk[r] = f2bf(o[qg][dc][mI * 4 + r] * inv);
        *(us4*)(aout + (size_t)qrow * 512 + h * 64 + dc * 32 + mI * 8 +
                hi * 4) = pk;
      }
  }
}

// ---------------------------------------------------------------- launch
extern "C" void kernel_launch(void* const* d_in, const int* in_sizes, int n_in,
                              void* d_out, int out_size, void* d_ws,
                              size_t ws_size, hipStream_t stream) {
  const float* x = (const float*)d_in[0];     // [4,2048,512]
  const int* mask = (const int*)d_in[1];      // [4,2048]
  const float* Wc = (const float*)d_in[2];    // [512,1536]
  const float* bc = (const float*)d_in[3];    // [1536]
  const float* Wo = (const float*)d_in[4];    // [512,512]
  const float* bo = (const float*)d_in[5];    // [512]
  float* out = (float*)d_out;                 // [4,2048,512] fp32

  char* ws = (char*)d_ws;
  u16* xbf = (u16*)(ws);                      //  8 MB [8192][512]
  u16* wct = (u16*)(ws + 8388608);            //  1.5 MB [1536][512]
  u16* wot = (u16*)(ws + 9961472);            //  0.5 MB [512][512]
  u16* Qc  = (u16*)(ws + 10485760);           //  8 MB (pre-scaled by log2e/8)
  u16* Kc  = (u16*)(ws + 18874368);           //  8 MB compact K
  u16* vtc = (u16*)(ws + 27262976);           //  8 MB compact V^T
  int* idx = (int*)(ws + 35651584);           // 32 KB
  int* nbv = (int*)(ws + 35684352);           // 16 B
  u16* aout = xbf;                            // reuse (xbf dead after gemms)

  prep<<<5124, 256, 0, stream>>>(x, Wc, Wo, mask, xbf, wct, wot, idx, nbv);
  gemm_qkv<<<768, 256, 0, stream>>>(xbf, wct, bc, Qc, Kc, vtc, idx, nbv);
  attn_kernel<<<dim3(8, 8, 4), 256, 0, stream>>>(Qc, Kc, vtc, nbv, aout);
  gemm_out<<<dim3(4, 64), 256, 0, stream>>>(aout, wot, bo, out);
}